// Round 8
// baseline (2498.848 us; speedup 1.0000x reference)
//
#include <hip/hip_runtime.h>
#include <math.h>

__device__ __forceinline__ float sigf(float x) { return 1.0f / (1.0f + expf(-x)); }

// ---------------- Encoder GEMM1: C = relu(X @ W + b) ----------------
// Round-6 exact config (measured 228us): 64x128 tiles, grid 1024, BK=16
__global__ __launch_bounds__(256) void k_gemm1(const float* __restrict__ X,
                                               const float* __restrict__ W,
                                               const float* __restrict__ Bv,
                                               float* __restrict__ C)
{
  const int K = 1024, N = 512;
  __shared__ float As[16][68];
  __shared__ float Bs[16][132];
  const int tid = threadIdx.x;
  const int bm = blockIdx.x >> 2;
  const int bn = blockIdx.x & 3;
  const int ty = tid >> 4, tx = tid & 15;
  const int ar = tid & 63, ac4 = (tid >> 6) * 4;
  const int bk = tid >> 4, bc8 = (tid & 15) * 8;
  const float* Xb = X + (size_t)(bm * 64 + ar) * K;
  float acc[4][8];
#pragma unroll
  for (int i = 0; i < 4; i++)
#pragma unroll
    for (int j = 0; j < 8; j++) acc[i][j] = 0.f;

  for (int k0 = 0; k0 < K; k0 += 16) {
    float4 av = *(const float4*)(Xb + k0 + ac4);
    float4 b0 = *(const float4*)(W + (size_t)(k0 + bk) * N + bn * 128 + bc8);
    float4 b1 = *(const float4*)(W + (size_t)(k0 + bk) * N + bn * 128 + bc8 + 4);
    As[ac4 + 0][ar] = av.x; As[ac4 + 1][ar] = av.y;
    As[ac4 + 2][ar] = av.z; As[ac4 + 3][ar] = av.w;
    *(float4*)(&Bs[bk][bc8]) = b0;
    *(float4*)(&Bs[bk][bc8 + 4]) = b1;
    __syncthreads();
#pragma unroll
    for (int kk = 0; kk < 16; kk++) {
      float4 a = *(const float4*)(&As[kk][ty * 4]);
      float4 bA = *(const float4*)(&Bs[kk][tx * 4]);
      float4 bB = *(const float4*)(&Bs[kk][64 + tx * 4]);
      float ar4[4] = {a.x, a.y, a.z, a.w};
#pragma unroll
      for (int i = 0; i < 4; i++) {
        acc[i][0] = fmaf(ar4[i], bA.x, acc[i][0]);
        acc[i][1] = fmaf(ar4[i], bA.y, acc[i][1]);
        acc[i][2] = fmaf(ar4[i], bA.z, acc[i][2]);
        acc[i][3] = fmaf(ar4[i], bA.w, acc[i][3]);
        acc[i][4] = fmaf(ar4[i], bB.x, acc[i][4]);
        acc[i][5] = fmaf(ar4[i], bB.y, acc[i][5]);
        acc[i][6] = fmaf(ar4[i], bB.z, acc[i][6]);
        acc[i][7] = fmaf(ar4[i], bB.w, acc[i][7]);
      }
    }
    __syncthreads();
  }
  const int crow0 = bm * 64 + ty * 4;
  const int ccolA = bn * 128 + tx * 4;
  const int ccolB = ccolA + 64;
  float4 bvA = *(const float4*)(Bv + ccolA);
  float4 bvB = *(const float4*)(Bv + ccolB);
#pragma unroll
  for (int i = 0; i < 4; i++) {
    float4 vA = make_float4(acc[i][0] + bvA.x, acc[i][1] + bvA.y,
                            acc[i][2] + bvA.z, acc[i][3] + bvA.w);
    float4 vB = make_float4(acc[i][4] + bvB.x, acc[i][5] + bvB.y,
                            acc[i][6] + bvB.z, acc[i][7] + bvB.w);
    vA.x = fmaxf(vA.x, 0.f); vA.y = fmaxf(vA.y, 0.f);
    vA.z = fmaxf(vA.z, 0.f); vA.w = fmaxf(vA.w, 0.f);
    vB.x = fmaxf(vB.x, 0.f); vB.y = fmaxf(vB.y, 0.f);
    vB.z = fmaxf(vB.z, 0.f); vB.w = fmaxf(vB.w, 0.f);
    *(float4*)(&C[(size_t)(crow0 + i) * N + ccolA]) = vA;
    *(float4*)(&C[(size_t)(crow0 + i) * N + ccolB]) = vB;
  }
}

// ---------------- Encoder GEMM2: zp = C1 @ W2 + b2; zp [512][32][128] ----------------
__global__ __launch_bounds__(256) void k_gemm2(const float* __restrict__ A,
                                               const float* __restrict__ W,
                                               const float* __restrict__ Bv,
                                               float* __restrict__ zp)
{
  const int K = 512, N = 128;
  __shared__ float As[16][36];
  __shared__ float Bs[16][132];
  const int tid = threadIdx.x;
  const int bm = blockIdx.x;
  const int ty = tid >> 4, tx = tid & 15;
  const int ar = tid & 31, ac4 = ((tid >> 5) & 3) * 4;
  const int bk = tid >> 4, bc8 = (tid & 15) * 8;
  float acc[2][8];
#pragma unroll
  for (int i = 0; i < 2; i++)
#pragma unroll
    for (int j = 0; j < 8; j++) acc[i][j] = 0.f;

  for (int k0 = 0; k0 < K; k0 += 16) {
    if (tid < 128) {
      float4 av = *(const float4*)(A + (size_t)(bm * 32 + ar) * K + k0 + ac4);
      As[ac4 + 0][ar] = av.x; As[ac4 + 1][ar] = av.y;
      As[ac4 + 2][ar] = av.z; As[ac4 + 3][ar] = av.w;
    }
    *(float4*)(&Bs[bk][bc8]) = *(const float4*)(W + (size_t)(k0 + bk) * N + bc8);
    *(float4*)(&Bs[bk][bc8 + 4]) = *(const float4*)(W + (size_t)(k0 + bk) * N + bc8 + 4);
    __syncthreads();
#pragma unroll
    for (int kk = 0; kk < 16; kk++) {
      float a0 = As[kk][ty * 2], a1 = As[kk][ty * 2 + 1];
      float4 bA = *(const float4*)(&Bs[kk][tx * 4]);
      float4 bB = *(const float4*)(&Bs[kk][64 + tx * 4]);
      acc[0][0] = fmaf(a0, bA.x, acc[0][0]); acc[0][1] = fmaf(a0, bA.y, acc[0][1]);
      acc[0][2] = fmaf(a0, bA.z, acc[0][2]); acc[0][3] = fmaf(a0, bA.w, acc[0][3]);
      acc[0][4] = fmaf(a0, bB.x, acc[0][4]); acc[0][5] = fmaf(a0, bB.y, acc[0][5]);
      acc[0][6] = fmaf(a0, bB.z, acc[0][6]); acc[0][7] = fmaf(a0, bB.w, acc[0][7]);
      acc[1][0] = fmaf(a1, bA.x, acc[1][0]); acc[1][1] = fmaf(a1, bA.y, acc[1][1]);
      acc[1][2] = fmaf(a1, bA.z, acc[1][2]); acc[1][3] = fmaf(a1, bA.w, acc[1][3]);
      acc[1][4] = fmaf(a1, bB.x, acc[1][4]); acc[1][5] = fmaf(a1, bB.y, acc[1][5]);
      acc[1][6] = fmaf(a1, bB.z, acc[1][6]); acc[1][7] = fmaf(a1, bB.w, acc[1][7]);
    }
    __syncthreads();
  }
  const int ccolA = tx * 4, ccolB = ccolA + 64;
  float4 bvA = *(const float4*)(Bv + ccolA);
  float4 bvB = *(const float4*)(Bv + ccolB);
#pragma unroll
  for (int i = 0; i < 2; i++) {
    int r = bm * 32 + ty * 2 + i;
    int b = r >> 5, tt = r & 31;
    float4 vA = make_float4(acc[i][0] + bvA.x, acc[i][1] + bvA.y,
                            acc[i][2] + bvA.z, acc[i][3] + bvA.w);
    float4 vB = make_float4(acc[i][4] + bvB.x, acc[i][5] + bvB.y,
                            acc[i][6] + bvB.z, acc[i][7] + bvB.w);
    *(float4*)(&zp[(size_t)b * 4096 + tt * 128 + ccolA]) = vA;
    *(float4*)(&zp[(size_t)b * 4096 + tt * 128 + ccolB]) = vB;
  }
}

// ---------------- Gram + softmax precompute ----------------
__global__ __launch_bounds__(256) void k_gram(const float* __restrict__ zp,
                                              float* __restrict__ warr,
                                              float* __restrict__ wc,
                                              const float* __restrict__ cgp,
                                              const float* __restrict__ cbp)
{
  __shared__ float zl[32][128];
  __shared__ float sg[32][32];
  int b = blockIdx.x, tid = threadIdx.x;
  const float* zb = zp + (size_t)b * 4096;
  for (int i = tid; i < 32 * 128; i += 256) (&zl[0][0])[i] = zb[i];
  __syncthreads();
  for (int p = tid; p < 496; p += 256) {
    int t = 1;
    while (p >= t * (t + 1) / 2) t++;
    int tp = p - t * (t - 1) / 2;
    const float* za = &zl[t][0];
    const float* zc = &zl[tp][0];
    float s = 0.f;
#pragma unroll 4
    for (int c = 0; c < 128; c += 4) {
      s += za[c] * zc[c] + za[c + 1] * zc[c + 1] + za[c + 2] * zc[c + 2] + za[c + 3] * zc[c + 3];
    }
    sg[t][tp] = s;
  }
  __syncthreads();
  if (tid >= 1 && tid < 32) {
    int t = tid;
    float cg = cgp[0], cb = cbp[0];
    float m = -3.0e38f;
    for (int tp = 0; tp < t; tp++) m = fmaxf(m, sg[t][tp]);
    float se = 0.f;
    for (int tp = 0; tp < t; tp++) se += expf(sg[t][tp] - m);
    float inv = 1.0f / se;
    float wcs = 0.f;
    for (int tp = 0; tp < t; tp++) {
      float s = sg[t][tp];
      float w = expf(s - m) * inv;
      warr[(size_t)b * 1024 + t * 32 + tp] = w;
      wcs = fmaf(w, sigf(fmaf(s, cg, cb)), wcs);
    }
    wc[b * 32 + t] = wcs;
  }
}

// ---------------- per-step gates: h = act(keyr @ Wx + b) ----------------
// grid 512 (32 rt x 16 ct), 256 thr, 2 WG/CU. Barrier-free k-loop:
// A (keyr, 16 rows) staged once in LDS (stride 17, conflict-free);
// B (Wx) streamed from L2 as float2 x3 gates. Thread owns 2hc x 3g.
__global__ __launch_bounds__(256) void k_gates(const float* __restrict__ Wx,
                                               const float* __restrict__ lb,
                                               const float* __restrict__ keyrT,
                                               float* __restrict__ h, int t)
{
  __shared__ float As[257 * 17 + 3];
  const int tid = threadIdx.x;
  const int rt = blockIdx.x >> 4;
  const int ct = blockIdx.x & 15;
  const int row0 = rt * 16;
  const int hc0 = ct * 32;
  const int r = tid >> 4;
  const int c2 = tid & 15;
  const int j0 = hc0 + c2 * 2;

  float aI0 = lb[j0],        aI1 = lb[j0 + 1];
  float aC0 = lb[1024 + j0], aC1 = lb[1024 + j0 + 1];
  float aO0 = lb[1536 + j0], aO1 = lb[1536 + j0 + 1];

  if (t > 0) {
    {  // stage keyr: As[k*17 + rr] = keyrT[k*512 + row0 + rr]
      const int k = tid;
      const float* src = keyrT + (size_t)k * 512 + row0;
      float4 v0 = *(const float4*)(src);
      float4 v1 = *(const float4*)(src + 4);
      float4 v2 = *(const float4*)(src + 8);
      float4 v3 = *(const float4*)(src + 12);
      float* d = &As[k * 17];
      d[0] = v0.x; d[1] = v0.y; d[2] = v0.z; d[3] = v0.w;
      d[4] = v1.x; d[5] = v1.y; d[6] = v1.z; d[7] = v1.w;
      d[8] = v2.x; d[9] = v2.y; d[10] = v2.z; d[11] = v2.w;
      d[12] = v3.x; d[13] = v3.y; d[14] = v3.z; d[15] = v3.w;
      if (tid == 0) {
        const float* s2 = keyrT + (size_t)256 * 512 + row0;
        float* d2 = &As[256 * 17];
#pragma unroll
        for (int j = 0; j < 16; ++j) d2[j] = s2[j];
      }
    }
    __syncthreads();
    const float* wp = Wx + j0;
    const float* ap = &As[r];
#pragma unroll 8
    for (int k = 0; k < 257; ++k) {
      float a = ap[k * 17];
      float2 wi = *(const float2*)(wp + (size_t)k * 2048);
      float2 wv = *(const float2*)(wp + (size_t)k * 2048 + 1024);
      float2 wo = *(const float2*)(wp + (size_t)k * 2048 + 1536);
      aI0 = fmaf(a, wi.x, aI0); aI1 = fmaf(a, wi.y, aI1);
      aC0 = fmaf(a, wv.x, aC0); aC1 = fmaf(a, wv.y, aC1);
      aO0 = fmaf(a, wo.x, aO0); aO1 = fmaf(a, wo.y, aO1);
    }
  }
  float h0 = sigf(aO0) * tanhf(sigf(aI0) * tanhf(aC0));
  float h1 = sigf(aO1) * tanhf(sigf(aI1) * tanhf(aC1));
  *(float2*)&h[(size_t)(row0 + r) * 512 + j0] = make_float2(h0, h1);
}

// ---------------- per-step update: keyw->Mk[t], gate, keyrT ----------------
// grid 512 (32 rt x 16 ct), 256 thr, 2 WG/CU. Barrier-light:
// h (16 rows) staged once; kW streamed from L2 (64B wave-broadcast lines).
__global__ __launch_bounds__(256) void k_update(const float* __restrict__ h,
                                                const float* __restrict__ kW,
                                                const float* __restrict__ kb,
                                                const float* __restrict__ gW,
                                                const float* __restrict__ gb,
                                                const float* __restrict__ warr,
                                                const float* __restrict__ wc,
                                                float* __restrict__ Mk,
                                                float* __restrict__ keyrT, int t)
{
  __shared__ float hs[16 * 516];
  __shared__ float gWs[512];
  __shared__ float wws[16 * 36];
  __shared__ float gsh[16];
  const int tid = threadIdx.x;
  const int rt = blockIdx.x >> 4;
  const int ct = blockIdx.x & 15;
  const int row0 = rt * 16;
  const int c0 = ct * 16;
  const int r = tid >> 4, c = tid & 15;

  {  // stage
    const float* hrow = h + (size_t)(row0 + r) * 512 + c * 32;
    float* hd = &hs[r * 516 + c * 32];
#pragma unroll
    for (int q = 0; q < 8; ++q) *(float4*)&hd[q * 4] = *(const float4*)&hrow[q * 4];
    if (tid < 128) *(float4*)&gWs[tid * 4] = *(const float4*)&gW[tid * 4];
    wws[r * 36 + c]      = (c < t)      ? warr[(size_t)(row0 + r) * 1024 + t * 32 + c] : 0.f;
    wws[r * 36 + 16 + c] = (16 + c < t) ? warr[(size_t)(row0 + r) * 1024 + t * 32 + 16 + c] : 0.f;
  }
  __syncthreads();

  // keyw: one output per thread, K=512, kW streamed (wave-coherent 64B lines)
  {
    float acc = kb[c0 + c];
    const float* hp = &hs[r * 516];
    const float* kp = kW + c0 + c;
#pragma unroll 8
    for (int k = 0; k < 512; ++k)
      acc = fmaf(hp[k], kp[(size_t)k * 256], acc);
    Mk[(size_t)(row0 + r) * 8192 + t * 256 + c0 + c] = acc;
  }
  // gate dot
  {
    float s = 0.f;
    const float* hp = &hs[r * 516];
#pragma unroll 8
    for (int k = c; k < 512; k += 16) s = fmaf(hp[k], gWs[k], s);
    s += __shfl_xor(s, 1); s += __shfl_xor(s, 2);
    s += __shfl_xor(s, 4); s += __shfl_xor(s, 8);
    if (c == 0) gsh[r] = sigf(s + gb[0]);
  }
  __syncthreads();
  // keyr update (transposed store)
  {
    const int row = row0 + r;
    if (t == 0) {
      keyrT[(size_t)(c0 + c) * 512 + row] = 0.f;
      if (ct == 0 && c == 0) keyrT[(size_t)256 * 512 + row] = 0.f;
    } else {
      float a = 0.f;
      const float* mkb = Mk + (size_t)row * 8192 + c0 + c;
      const float* wp = &wws[r * 36];
      for (int tp = 0; tp < t; ++tp) a = fmaf(wp[tp], mkb[tp * 256], a);
      float g = gsh[r];
      keyrT[(size_t)(c0 + c) * 512 + row] = g * a;
      if (ct == 0 && c == 0)
        keyrT[(size_t)256 * 512 + row] = g * wc[row * 32 + t];
    }
  }
}

// ---------------- final: y = h @ yW + yb, argmax ----------------
__global__ __launch_bounds__(256) void k_y(const float* __restrict__ h,
                                           const float* __restrict__ yW,
                                           const float* __restrict__ yb,
                                           float* __restrict__ out)
{
  int tid = threadIdx.x;
  int wave = tid >> 6, lane = tid & 63;
  int row = blockIdx.x * 4 + wave;
  float a0 = 0.f, a1 = 0.f, a2 = 0.f, a3 = 0.f;
  for (int k = lane; k < 512; k += 64) {
    float hv = h[(size_t)row * 512 + k];
    float4 w4 = *(const float4*)(yW + k * 4);
    a0 = fmaf(hv, w4.x, a0);
    a1 = fmaf(hv, w4.y, a1);
    a2 = fmaf(hv, w4.z, a2);
    a3 = fmaf(hv, w4.w, a3);
  }
#pragma unroll
  for (int off = 32; off > 0; off >>= 1) {
    a0 += __shfl_xor(a0, off);
    a1 += __shfl_xor(a1, off);
    a2 += __shfl_xor(a2, off);
    a3 += __shfl_xor(a3, off);
  }
  if (lane == 0) {
    a0 += yb[0]; a1 += yb[1]; a2 += yb[2]; a3 += yb[3];
    out[row * 4 + 0] = a0;
    out[row * 4 + 1] = a1;
    out[row * 4 + 2] = a2;
    out[row * 4 + 3] = a3;
    int bi = 0; float bv = a0;
    if (a1 > bv) { bv = a1; bi = 1; }
    if (a2 > bv) { bv = a2; bi = 2; }
    if (a3 > bv) { bv = a3; bi = 3; }
    out[2048 + row] = (float)bi;
  }
}

extern "C" void kernel_launch(void* const* d_in, const int* in_sizes, int n_in,
                              void* d_out, int out_size, void* d_ws, size_t ws_size,
                              hipStream_t stream)
{
  const float* x  = (const float*)d_in[0];
  const float* w1 = (const float*)d_in[1];
  const float* b1 = (const float*)d_in[2];
  const float* w2 = (const float*)d_in[3];
  const float* b2 = (const float*)d_in[4];
  const float* Wx = (const float*)d_in[5];
  const float* lb = (const float*)d_in[6];
  const float* kW = (const float*)d_in[7];
  const float* kb = (const float*)d_in[8];
  const float* gW = (const float*)d_in[9];
  const float* gb = (const float*)d_in[10];
  const float* yW = (const float*)d_in[11];
  const float* yb = (const float*)d_in[12];
  const float* cg = (const float*)d_in[13];
  const float* cb = (const float*)d_in[14];
  float* out = (float*)d_out;
  char* ws = (char*)d_ws;
  // ws layout:
  //  C1 @ [0, 33.55MB)  (dead after k_gemm2; region reused below)
  //    Mk    @ 0          (16.78MB)  [512][32][256]
  //    warr  @ 16777216   (2MB)      [512][32][32]
  //    wc    @ 18874368   (64KB)     [512][32]
  //    keyrT @ 18939904   (526KB)    [257][512]
  //    h     @ 19466240   (1MB)      [512][512]
  //  zp @ 33554432        (8.4MB)    [512][32][128]
  float* C1    = (float*)(ws);
  float* Mk    = (float*)(ws);
  float* warr  = (float*)(ws + 16777216);
  float* wcb   = (float*)(ws + 18874368);
  float* keyrT = (float*)(ws + 18939904);
  float* h     = (float*)(ws + 19466240);
  float* zp    = (float*)(ws + 33554432);

  hipLaunchKernelGGL(k_gemm1, dim3(1024), dim3(256), 0, stream, x, w1, b1, C1);
  hipLaunchKernelGGL(k_gemm2, dim3(512), dim3(256), 0, stream, C1, w2, b2, zp);
  hipLaunchKernelGGL(k_gram, dim3(512), dim3(256), 0, stream, zp, warr, wcb, cg, cb);
  for (int t = 0; t <= 32; t++) {
    hipLaunchKernelGGL(k_gates, dim3(512), dim3(256), 0, stream, Wx, lb, keyrT, h, t);
    if (t < 32) {
      hipLaunchKernelGGL(k_update, dim3(512), dim3(256), 0, stream,
                         h, kW, kb, gW, gb, warr, wcb, Mk, keyrT, t);
    }
  }
  hipLaunchKernelGGL(k_y, dim3(128), dim3(256), 0, stream, h, yW, yb, out);
}

// Round 9
// 1702.738 us; speedup vs baseline: 1.4675x; 1.4675x over previous
//
#include <hip/hip_runtime.h>
#include <math.h>

__device__ __forceinline__ float sigf(float x) { return 1.0f / (1.0f + expf(-x)); }

// ---------------- Encoder GEMM1: C = relu(X @ W + b) ----------------
// Round-6 exact config (measured 228us): 64x128 tiles, grid 1024, BK=16
__global__ __launch_bounds__(256) void k_gemm1(const float* __restrict__ X,
                                               const float* __restrict__ W,
                                               const float* __restrict__ Bv,
                                               float* __restrict__ C)
{
  const int K = 1024, N = 512;
  __shared__ float As[16][68];
  __shared__ float Bs[16][132];
  const int tid = threadIdx.x;
  const int bm = blockIdx.x >> 2;
  const int bn = blockIdx.x & 3;
  const int ty = tid >> 4, tx = tid & 15;
  const int ar = tid & 63, ac4 = (tid >> 6) * 4;
  const int bk = tid >> 4, bc8 = (tid & 15) * 8;
  const float* Xb = X + (size_t)(bm * 64 + ar) * K;
  float acc[4][8];
#pragma unroll
  for (int i = 0; i < 4; i++)
#pragma unroll
    for (int j = 0; j < 8; j++) acc[i][j] = 0.f;

  for (int k0 = 0; k0 < K; k0 += 16) {
    float4 av = *(const float4*)(Xb + k0 + ac4);
    float4 b0 = *(const float4*)(W + (size_t)(k0 + bk) * N + bn * 128 + bc8);
    float4 b1 = *(const float4*)(W + (size_t)(k0 + bk) * N + bn * 128 + bc8 + 4);
    As[ac4 + 0][ar] = av.x; As[ac4 + 1][ar] = av.y;
    As[ac4 + 2][ar] = av.z; As[ac4 + 3][ar] = av.w;
    *(float4*)(&Bs[bk][bc8]) = b0;
    *(float4*)(&Bs[bk][bc8 + 4]) = b1;
    __syncthreads();
#pragma unroll
    for (int kk = 0; kk < 16; kk++) {
      float4 a = *(const float4*)(&As[kk][ty * 4]);
      float4 bA = *(const float4*)(&Bs[kk][tx * 4]);
      float4 bB = *(const float4*)(&Bs[kk][64 + tx * 4]);
      float ar4[4] = {a.x, a.y, a.z, a.w};
#pragma unroll
      for (int i = 0; i < 4; i++) {
        acc[i][0] = fmaf(ar4[i], bA.x, acc[i][0]);
        acc[i][1] = fmaf(ar4[i], bA.y, acc[i][1]);
        acc[i][2] = fmaf(ar4[i], bA.z, acc[i][2]);
        acc[i][3] = fmaf(ar4[i], bA.w, acc[i][3]);
        acc[i][4] = fmaf(ar4[i], bB.x, acc[i][4]);
        acc[i][5] = fmaf(ar4[i], bB.y, acc[i][5]);
        acc[i][6] = fmaf(ar4[i], bB.z, acc[i][6]);
        acc[i][7] = fmaf(ar4[i], bB.w, acc[i][7]);
      }
    }
    __syncthreads();
  }
  const int crow0 = bm * 64 + ty * 4;
  const int ccolA = bn * 128 + tx * 4;
  const int ccolB = ccolA + 64;
  float4 bvA = *(const float4*)(Bv + ccolA);
  float4 bvB = *(const float4*)(Bv + ccolB);
#pragma unroll
  for (int i = 0; i < 4; i++) {
    float4 vA = make_float4(acc[i][0] + bvA.x, acc[i][1] + bvA.y,
                            acc[i][2] + bvA.z, acc[i][3] + bvA.w);
    float4 vB = make_float4(acc[i][4] + bvB.x, acc[i][5] + bvB.y,
                            acc[i][6] + bvB.z, acc[i][7] + bvB.w);
    vA.x = fmaxf(vA.x, 0.f); vA.y = fmaxf(vA.y, 0.f);
    vA.z = fmaxf(vA.z, 0.f); vA.w = fmaxf(vA.w, 0.f);
    vB.x = fmaxf(vB.x, 0.f); vB.y = fmaxf(vB.y, 0.f);
    vB.z = fmaxf(vB.z, 0.f); vB.w = fmaxf(vB.w, 0.f);
    *(float4*)(&C[(size_t)(crow0 + i) * N + ccolA]) = vA;
    *(float4*)(&C[(size_t)(crow0 + i) * N + ccolB]) = vB;
  }
}

// ---------------- weight repack: WxP[k][j][3] (i,c,o), kWP[c][k] ----------------
__global__ __launch_bounds__(256) void k_pack(const float* __restrict__ Wx,
                                              const float* __restrict__ kW,
                                              float* __restrict__ WxP,
                                              float* __restrict__ kWP)
{
  int idx = blockIdx.x * 256 + threadIdx.x;
  if (idx < 257 * 512) {
    int k = idx >> 9, j = idx & 511;
    WxP[(size_t)idx * 3 + 0] = Wx[(size_t)k * 2048 + j];
    WxP[(size_t)idx * 3 + 1] = Wx[(size_t)k * 2048 + 1024 + j];
    WxP[(size_t)idx * 3 + 2] = Wx[(size_t)k * 2048 + 1536 + j];
  }
  if (idx < 512 * 256) {
    int k = idx >> 8, c = idx & 255;
    kWP[(size_t)c * 512 + k] = kW[idx];
  }
}

// ---------------- Encoder GEMM2 + fused Gram/softmax ----------------
// grid 512: WG bm owns batch row bm (rows bm*32..+32 of C1 = its 32 timesteps).
// Computes z-tile into LDS, then Gram + softmax weights directly (no zp global).
__global__ __launch_bounds__(256) void k_gemm2g(const float* __restrict__ A,
                                                const float* __restrict__ W,
                                                const float* __restrict__ Bv,
                                                float* __restrict__ warr,
                                                float* __restrict__ wc,
                                                const float* __restrict__ cgp,
                                                const float* __restrict__ cbp)
{
  const int K = 512, N = 128;
  __shared__ float As[16][36];
  __shared__ float Bs[16][132];
  __shared__ float zL[32][132];
  __shared__ float sg[32][33];
  const int tid = threadIdx.x;
  const int bm = blockIdx.x;
  const int ty = tid >> 4, tx = tid & 15;
  const int ar = tid & 31, ac4 = ((tid >> 5) & 3) * 4;
  const int bk = tid >> 4, bc8 = (tid & 15) * 8;
  float acc[2][8];
#pragma unroll
  for (int i = 0; i < 2; i++)
#pragma unroll
    for (int j = 0; j < 8; j++) acc[i][j] = 0.f;

  for (int k0 = 0; k0 < K; k0 += 16) {
    if (tid < 128) {
      float4 av = *(const float4*)(A + (size_t)(bm * 32 + ar) * K + k0 + ac4);
      As[ac4 + 0][ar] = av.x; As[ac4 + 1][ar] = av.y;
      As[ac4 + 2][ar] = av.z; As[ac4 + 3][ar] = av.w;
    }
    *(float4*)(&Bs[bk][bc8]) = *(const float4*)(W + (size_t)(k0 + bk) * N + bc8);
    *(float4*)(&Bs[bk][bc8 + 4]) = *(const float4*)(W + (size_t)(k0 + bk) * N + bc8 + 4);
    __syncthreads();
#pragma unroll
    for (int kk = 0; kk < 16; kk++) {
      float a0 = As[kk][ty * 2], a1 = As[kk][ty * 2 + 1];
      float4 bA = *(const float4*)(&Bs[kk][tx * 4]);
      float4 bB = *(const float4*)(&Bs[kk][64 + tx * 4]);
      acc[0][0] = fmaf(a0, bA.x, acc[0][0]); acc[0][1] = fmaf(a0, bA.y, acc[0][1]);
      acc[0][2] = fmaf(a0, bA.z, acc[0][2]); acc[0][3] = fmaf(a0, bA.w, acc[0][3]);
      acc[0][4] = fmaf(a0, bB.x, acc[0][4]); acc[0][5] = fmaf(a0, bB.y, acc[0][5]);
      acc[0][6] = fmaf(a0, bB.z, acc[0][6]); acc[0][7] = fmaf(a0, bB.w, acc[0][7]);
      acc[1][0] = fmaf(a1, bA.x, acc[1][0]); acc[1][1] = fmaf(a1, bA.y, acc[1][1]);
      acc[1][2] = fmaf(a1, bA.z, acc[1][2]); acc[1][3] = fmaf(a1, bA.w, acc[1][3]);
      acc[1][4] = fmaf(a1, bB.x, acc[1][4]); acc[1][5] = fmaf(a1, bB.y, acc[1][5]);
      acc[1][6] = fmaf(a1, bB.z, acc[1][6]); acc[1][7] = fmaf(a1, bB.w, acc[1][7]);
    }
    __syncthreads();
  }
  const int ccolA = tx * 4, ccolB = ccolA + 64;
  float4 bvA = *(const float4*)(Bv + ccolA);
  float4 bvB = *(const float4*)(Bv + ccolB);
#pragma unroll
  for (int i = 0; i < 2; i++) {
    int rr = ty * 2 + i;
    *(float4*)(&zL[rr][ccolA]) = make_float4(acc[i][0] + bvA.x, acc[i][1] + bvA.y,
                                             acc[i][2] + bvA.z, acc[i][3] + bvA.w);
    *(float4*)(&zL[rr][ccolB]) = make_float4(acc[i][4] + bvB.x, acc[i][5] + bvB.y,
                                             acc[i][6] + bvB.z, acc[i][7] + bvB.w);
  }
  __syncthreads();
  // Gram: sg[t][tp] = z_t . z_tp for tp < t
  for (int p = tid; p < 496; p += 256) {
    int t = 1;
    while (p >= t * (t + 1) / 2) t++;
    int tp = p - t * (t - 1) / 2;
    const float* za = &zL[t][0];
    const float* zc = &zL[tp][0];
    float s = 0.f;
#pragma unroll 4
    for (int c = 0; c < 128; c += 4) {
      s += za[c] * zc[c] + za[c + 1] * zc[c + 1] + za[c + 2] * zc[c + 2] + za[c + 3] * zc[c + 3];
    }
    sg[t][tp] = s;
  }
  __syncthreads();
  if (tid >= 1 && tid < 32) {
    int t = tid;
    float cg = cgp[0], cb = cbp[0];
    float m = -3.0e38f;
    for (int tp = 0; tp < t; tp++) m = fmaxf(m, sg[t][tp]);
    float se = 0.f;
    for (int tp = 0; tp < t; tp++) se += expf(sg[t][tp] - m);
    float inv = 1.0f / se;
    float wcs = 0.f;
    for (int tp = 0; tp < t; tp++) {
      float s = sg[t][tp];
      float w = expf(s - m) * inv;
      warr[(size_t)bm * 1024 + t * 32 + tp] = w;
      wcs = fmaf(w, sigf(fmaf(s, cg, cb)), wcs);
    }
    wc[bm * 32 + t] = wcs;
  }
}

// ---------------- persistent scan: 256 WGs x 512 thr, 2 batch rows/WG ----------------
// ALL state in LDS (Mk 64KB, keyr, h). Zero cross-WG traffic, zero launches.
// Per step: G (gates GEMM, WxP stream) -> K (keyw, kWP stream) + gate -> P (keyr).
__global__ __launch_bounds__(512) void k_scan(
    const float* __restrict__ WxP, const float* __restrict__ lb,
    const float* __restrict__ kWP, const float* __restrict__ kb,
    const float* __restrict__ gW, const float* __restrict__ gb,
    const float* __restrict__ yW, const float* __restrict__ yb,
    const float* __restrict__ warr, const float* __restrict__ wc,
    float* __restrict__ out)
{
  __shared__ float MkL[2][32][256];   // 64KB: the whole key memory for 2 rows
  __shared__ float hL[2][512];
  __shared__ float krL[257][2];
  __shared__ float lbL[3][512];
  __shared__ float gWL[512];
  __shared__ float kbL[256];
  __shared__ float wwL[2][32];
  __shared__ float red[8];
  __shared__ float red4[8][4];
  __shared__ float gL[2];
  const int tid = threadIdx.x;
  const int row0 = blockIdx.x * 2;
  const int r = tid >> 8;        // 0..1 (wave-uniform)
  const int c = tid & 255;       // 0..255
  const float gbv = gb[0];

  // persistent staging
  lbL[0][tid] = lb[tid];
  lbL[1][tid] = lb[1024 + tid];
  lbL[2][tid] = lb[1536 + tid];
  gWL[tid] = gW[tid];
  if (tid < 256) kbL[tid] = kb[tid];
  if (tid < 257) { krL[tid][0] = 0.f; krL[tid][1] = 0.f; }
  __syncthreads();

  for (int t = 0; t <= 32; ++t) {
    // ---------- G: h = act(keyr @ Wx + b), both rows, col=tid ----------
    float h0, h1;
    if (t >= 2) {
      float aI0 = lbL[0][tid], aI1 = aI0;
      float aC0 = lbL[1][tid], aC1 = aC0;
      float aO0 = lbL[2][tid], aO1 = aO0;
      const float* wp = WxP + (size_t)tid * 3;
#pragma unroll 8
      for (int k = 0; k < 257; ++k) {
        float2 a01 = *(const float2*)&krL[k][0];
        float wi = wp[0], wcv = wp[1], wo = wp[2];
        aI0 = fmaf(a01.x, wi, aI0);  aI1 = fmaf(a01.y, wi, aI1);
        aC0 = fmaf(a01.x, wcv, aC0); aC1 = fmaf(a01.y, wcv, aC1);
        aO0 = fmaf(a01.x, wo, aO0);  aO1 = fmaf(a01.y, wo, aO1);
        wp += 1536;
      }
      h0 = sigf(aO0) * tanhf(sigf(aI0) * tanhf(aC0));
      h1 = sigf(aO1) * tanhf(sigf(aI1) * tanhf(aC1));
    } else {
      float hb = sigf(lbL[2][tid]) * tanhf(sigf(lbL[0][tid]) * tanhf(lbL[1][tid]));
      h0 = hb; h1 = hb;
    }
    hL[0][tid] = h0;
    hL[1][tid] = h1;
    __syncthreads();
    if (t == 32) break;

    // ---------- K: keyw -> MkL[r][t][c]; gate partial; wwL stage ----------
    {
      float acc = kbL[c];
      const float* kp = kWP + (size_t)c * 512;
      const float* hp = &hL[r][0];
#pragma unroll 8
      for (int k = 0; k < 512; k += 4) {
        float4 kw4 = *(const float4*)(kp + k);
        float4 h4 = *(const float4*)(hp + k);
        acc = fmaf(h4.x, kw4.x, acc);
        acc = fmaf(h4.y, kw4.y, acc);
        acc = fmaf(h4.z, kw4.z, acc);
        acc = fmaf(h4.w, kw4.w, acc);
      }
      MkL[r][t][c] = acc;
    }
    {
      float gs = hL[r][c] * gWL[c] + hL[r][c + 256] * gWL[c + 256];
#pragma unroll
      for (int off = 32; off > 0; off >>= 1) gs += __shfl_xor(gs, off);
      if ((tid & 63) == 0) red[tid >> 6] = gs;
    }
    if (tid >= 64 && tid < 128) {
      int q = tid - 64;
      int rr = q >> 5, tp = q & 31;
      wwL[rr][tp] = (tp < t) ? warr[(size_t)(row0 + rr) * 1024 + t * 32 + tp] : 0.f;
    }
    __syncthreads();
    if (tid < 2)
      gL[tid] = sigf(red[tid * 4] + red[tid * 4 + 1] + red[tid * 4 + 2] + red[tid * 4 + 3] + gbv);
    __syncthreads();

    // ---------- P: keyr = g * sum_tp w[t][tp] * MkL[tp] ----------
    if (t >= 1) {
      float a = 0.f;
      const float* wp2 = &wwL[r][0];
      for (int tp = 0; tp < t; ++tp) a = fmaf(wp2[tp], MkL[r][tp][c], a);
      krL[c][r] = gL[r] * a;
      if (tid < 2) krL[256][tid] = gL[tid] * wc[(row0 + tid) * 32 + t];
    }
    __syncthreads();
  }

  // ---------- y = h(32) @ yW + yb, argmax ----------
  {
    float hv0 = hL[r][c], hv1 = hL[r][c + 256];
    float4 w0 = *(const float4*)(yW + c * 4);
    float4 w1 = *(const float4*)(yW + (c + 256) * 4);
    float px = hv0 * w0.x + hv1 * w1.x;
    float py = hv0 * w0.y + hv1 * w1.y;
    float pz = hv0 * w0.z + hv1 * w1.z;
    float pw = hv0 * w0.w + hv1 * w1.w;
#pragma unroll
    for (int off = 32; off > 0; off >>= 1) {
      px += __shfl_xor(px, off);
      py += __shfl_xor(py, off);
      pz += __shfl_xor(pz, off);
      pw += __shfl_xor(pw, off);
    }
    if ((tid & 63) == 0) {
      int w = tid >> 6;
      red4[w][0] = px; red4[w][1] = py; red4[w][2] = pz; red4[w][3] = pw;
    }
    __syncthreads();
    if (tid < 2) {
      float a0 = red4[tid * 4][0] + red4[tid * 4 + 1][0] + red4[tid * 4 + 2][0] + red4[tid * 4 + 3][0] + yb[0];
      float a1 = red4[tid * 4][1] + red4[tid * 4 + 1][1] + red4[tid * 4 + 2][1] + red4[tid * 4 + 3][1] + yb[1];
      float a2 = red4[tid * 4][2] + red4[tid * 4 + 1][2] + red4[tid * 4 + 2][2] + red4[tid * 4 + 3][2] + yb[2];
      float a3 = red4[tid * 4][3] + red4[tid * 4 + 1][3] + red4[tid * 4 + 2][3] + red4[tid * 4 + 3][3] + yb[3];
      const int row = row0 + tid;
      out[row * 4 + 0] = a0;
      out[row * 4 + 1] = a1;
      out[row * 4 + 2] = a2;
      out[row * 4 + 3] = a3;
      int bi = 0; float bv = a0;
      if (a1 > bv) { bv = a1; bi = 1; }
      if (a2 > bv) { bv = a2; bi = 2; }
      if (a3 > bv) { bv = a3; bi = 3; }
      out[2048 + row] = (float)bi;
    }
  }
}

extern "C" void kernel_launch(void* const* d_in, const int* in_sizes, int n_in,
                              void* d_out, int out_size, void* d_ws, size_t ws_size,
                              hipStream_t stream)
{
  const float* x  = (const float*)d_in[0];
  const float* w1 = (const float*)d_in[1];
  const float* b1 = (const float*)d_in[2];
  const float* w2 = (const float*)d_in[3];
  const float* b2 = (const float*)d_in[4];
  const float* Wx = (const float*)d_in[5];
  const float* lb = (const float*)d_in[6];
  const float* kW = (const float*)d_in[7];
  const float* kb = (const float*)d_in[8];
  const float* gW = (const float*)d_in[9];
  const float* gb = (const float*)d_in[10];
  const float* yW = (const float*)d_in[11];
  const float* yb = (const float*)d_in[12];
  const float* cg = (const float*)d_in[13];
  const float* cb = (const float*)d_in[14];
  float* out = (float*)d_out;
  char* ws = (char*)d_ws;
  // ws layout:
  //  C1   @ 0          33554432  [16384][512] (encoder hidden; input to k_gemm2g)
  //  warr @ 33554432   2097152   [512][32][32]
  //  wc   @ 35651584   65536     [512][32]
  //  WxP  @ 35717120   1579008   [257][512][3]  (i,c,o packed)
  //  kWP  @ 37298176   524288    [256][512]     (kW transposed)
  float* C1   = (float*)(ws);
  float* warr = (float*)(ws + 33554432);
  float* wcb  = (float*)(ws + 35651584);
  float* WxP  = (float*)(ws + 35717120);
  float* kWP  = (float*)(ws + 37298176);

  hipLaunchKernelGGL(k_gemm1, dim3(1024), dim3(256), 0, stream, x, w1, b1, C1);
  hipLaunchKernelGGL(k_pack, dim3(514), dim3(256), 0, stream, Wx, kW, WxP, kWP);
  hipLaunchKernelGGL(k_gemm2g, dim3(512), dim3(256), 0, stream, C1, w2, b2, warr, wcb, cg, cb);
  hipLaunchKernelGGL(k_scan, dim3(256), dim3(512), 0, stream,
                     WxP, lb, kWP, kb, gW, gb, yW, yb, warr, wcb, out);
}